// Round 11
// baseline (652.595 us; speedup 1.0000x reference)
//
#include <hip/hip_runtime.h>
#include <stdint.h>

typedef unsigned short u16;
typedef short bf16x8 __attribute__((ext_vector_type(8)));
typedef float f32x4  __attribute__((ext_vector_type(4)));
typedef uint32_t u32x4 __attribute__((ext_vector_type(4)));

#define MFMA16(a,b,c) __builtin_amdgcn_mfma_f32_16x16x32_bf16((a),(b),(c),0,0,0)

#define B_    4096
#define S_    50
#define V_    50000
#define VP_   50048     // 1564 * 32
#define KH    160       // padded h width (154 -> 160)
#define KY    640       // padded y1 width (616 -> 640)
#define KWP   168       // padded fc-weight row stride (elems)
#define BNF   32        // fc N-subtile rows (32 -> acc[4][2], ~120 VGPR)
#define NSUB  1564      // VP_/BNF
#define NCHUNK 64       // fc N-chunks: grid 16*64=1024 -> 4 blocks/CU
#define TILE_U16 (BNF * KWP)        // 5376 elems, 10752 B
#define TILE_LD  (TILE_U16 * 2 / 16) // 672 lane-loads
#define LD_PER_T 3
#define YS    648       // y1 LDS row stride

#define NB_FC  8211     // ceil(VP_*KWP/4/256)
#define NB_RES 4800     // 2*6*KY*KH/256
#define NB_BIA 19

static __device__ __forceinline__ u16 f2bf(float f) {
  union { float f; uint32_t u; } v; v.f = f;
  uint32_t u = v.u;
  return (u16)((u + 0x7FFFu + ((u >> 16) & 1u)) >> 16);   // RNE
}
static __device__ __forceinline__ float bf2f(u16 b) {
  union { uint32_t u; float f; } v; v.u = ((uint32_t)b) << 16; return v.f;
}

// ---------------- merged prep kernel (trunk weights: hi plane only) ----------------

__global__ __launch_bounds__(256) void prep_all_k(const float* __restrict__ fcw, u16* __restrict__ fcwb,
                                                  const float* __restrict__ rw1, const float* __restrict__ rw2,
                                                  u16* __restrict__ W1h, u16* __restrict__ W2h,
                                                  const float* __restrict__ rb1, const float* __restrict__ rb2,
                                                  float* __restrict__ b1p, float* __restrict__ b2p) {
  int bid = blockIdx.x, t = threadIdx.x;
  if (bid < NB_FC) {
    int e4 = (bid * 256 + t) * 4;
    if (e4 >= VP_ * KWP) return;
    int v = e4 / KWP, c = e4 - v * KWP;
    u16 o[4];
    #pragma unroll
    for (int i = 0; i < 4; ++i) {
      float x = (v < V_ && (c + i) < 154) ? fcw[(size_t)v * 154 + c + i] : 0.f;
      o[i] = f2bf(x);
    }
    *(uint2*)(fcwb + e4) = make_uint2((uint32_t)o[0] | ((uint32_t)o[1] << 16),
                                      (uint32_t)o[2] | ((uint32_t)o[3] << 16));
  } else if (bid < NB_FC + NB_RES) {
    int e = (bid - NB_FC) * 256 + t;
    const int NW = 6 * KY * KH;
    if (e < NW) {
      int k = e % KH, n = (e / KH) % KY, i = e / (KH * KY);
      float x = (n < 616 && k < 154) ? rw1[((size_t)i * 616 + n) * 154 + k] : 0.f;
      W1h[e] = f2bf(x);
    } else {
      int e2 = e - NW;
      int k = e2 % KY, n = (e2 / KY) % KH, i = e2 / (KH * KY);
      float x = (n < 154 && k < 616) ? rw2[((size_t)i * 154 + n) * 616 + k] : 0.f;
      W2h[e2] = f2bf(x);
    }
  } else {
    int e = (bid - NB_FC - NB_RES) * 256 + t;
    if (e < 6 * KY) {
      int i = e / KY, n = e % KY;
      b1p[e] = (n < 616) ? rb1[i * 616 + n] : 0.f;
    } else if (e < 6 * KY + 6 * KH) {
      int e2 = e - 6 * KY;
      int i = e2 / KH, n = e2 % KH;
      b2p[e2] = (n < 154) ? rb2[i * 154 + n] : 0.f;
    }
  }
}

// ---------------- h0: embed gather + masked mean + SE gate (f32 out) ----------------

__global__ __launch_bounds__(192) void h0_k(const float* __restrict__ inp, const int* __restrict__ mask,
                                            const float* __restrict__ embed,
                                            const float* __restrict__ sw1, const float* __restrict__ sb1,
                                            const float* __restrict__ sw2, const float* __restrict__ sb2,
                                            float* __restrict__ Hf) {
  int b = blockIdx.x, t = threadIdx.x;
  __shared__ float in_s[S_ * 28];
  __shared__ int   ids[S_];
  __shared__ float h_s[160];
  __shared__ float means[6];
  __shared__ int   len_s;
  const float* row = inp + (size_t)b * S_ * 28;
  for (int i = t; i < S_ * 28; i += 192) in_s[i] = row[i];
  int msum = 0;
  if (t < S_) msum = mask[b * S_ + t];
  __syncthreads();
  if (t < 64) {
    for (int off = 32; off; off >>= 1) msum += __shfl_down(msum, off);
    if (t == 0) len_s = msum;
  }
  if (t < S_) ids[t] = (int)in_s[t * 28];
  __syncthreads();
  int len = len_s;
  if (t < 154) {
    float val;
    if (t < 77) {
      float s = 0.f;
      if (t < 50) { for (int si = 0; si < len; ++si) s += embed[(size_t)ids[si] * 50 + t]; }
      else        { for (int si = 0; si < len; ++si) s += in_s[si * 28 + 1 + (t - 50)]; }
      val = s / (float)len;
    } else {
      int k2 = t - 77;
      val = (k2 < 50) ? embed[(size_t)ids[S_ - 1] * 50 + k2] : in_s[(S_ - 1) * 28 + 1 + (k2 - 50)];
    }
    h_s[t] = val;
  }
  __syncthreads();
  if (t < 6) {
    const int bnd[7] = {0, 50, 56, 77, 127, 133, 154};
    float s = 0.f;
    for (int k = bnd[t]; k < bnd[t + 1]; ++k) s += h_s[k];
    means[t] = s / (float)(bnd[t + 1] - bnd[t]);
  }
  __syncthreads();
  if (t < 160) {
    float o = 0.f;
    if (t < 154) {
      int seg = (t < 50) ? 0 : (t < 56) ? 1 : (t < 77) ? 2 : (t < 127) ? 3 : (t < 133) ? 4 : 5;
      float r0 = sb1[0], r1 = sb1[1];
      #pragma unroll
      for (int j = 0; j < 6; ++j) { r0 += sw1[j] * means[j]; r1 += sw1[6 + j] * means[j]; }
      r0 = fmaxf(r0, 0.f); r1 = fmaxf(r1, 0.f);
      float z = sw2[seg * 2 + 0] * r0 + sw2[seg * 2 + 1] * r1 + sb2[seg];
      float gate = 1.f / (1.f + __expf(-z));
      o = h_s[t] * gate;
    }
    Hf[(size_t)b * KH + t] = o;
  }
}

// ---------------- fused trunk: 6 resblocks, h in f32 LDS, plain bf16 GEMMs ----------------

__global__ __launch_bounds__(640, 1) void trunk_k(const u16* __restrict__ W1h_,
                                                  const u16* __restrict__ W2h_,
                                                  const float* __restrict__ b1p, const float* __restrict__ b2p,
                                                  const float* __restrict__ Hf, u16* __restrict__ Hh) {
  __shared__ __align__(16) float sH[16 * 164];
  __shared__ __align__(16) u16 sYh[16 * YS];
  int t = threadIdx.x, mb = blockIdx.x;
  int w = t >> 6, lane = t & 63, lr = lane & 15, lk = lane >> 4;
  {
    int r = t / 40, c4 = (t % 40) * 4;
    *(f32x4*)(sH + r * 164 + c4) = *(const f32x4*)(Hf + (size_t)(mb * 16 + r) * KH + c4);
  }
  __syncthreads();
  for (int i = 0; i < 6; ++i) {
    const u16* w1h = W1h_ + (size_t)i * KY * KH;
    const u16* w2h = W2h_ + (size_t)i * KH * KY;
    const float* b1 = b1p + i * KY;
    const float* b2 = b2p + i * KH;
    bf16x8 hh[5];
    #pragma unroll
    for (int ks = 0; ks < 5; ++ks) {
      int k0 = ks * 32 + lk * 8;
      f32x4 a = *(const f32x4*)(sH + lr * 164 + k0);
      f32x4 b = *(const f32x4*)(sH + lr * 164 + k0 + 4);
      bf16x8 hv;
      #pragma unroll
      for (int e = 0; e < 4; ++e) {
        hv[e] = (short)f2bf(a[e]);
        hv[4 + e] = (short)f2bf(b[e]);
      }
      hh[ks] = hv;
    }
    f32x4 acc1[4];
    #pragma unroll
    for (int nt = 0; nt < 4; ++nt) acc1[nt] = (f32x4){0.f,0.f,0.f,0.f};
    #pragma unroll
    for (int ks = 0; ks < 5; ++ks) {
      int k0 = ks * 32 + lk * 8;
      #pragma unroll
      for (int nt = 0; nt < 4; ++nt) {
        size_t ro = (size_t)((w * 4 + nt) * 16 + lr) * KH + k0;
        bf16x8 wh = *(const bf16x8*)(w1h + ro);
        acc1[nt] = MFMA16(wh, hh[ks], acc1[nt]);
      }
    }
    #pragma unroll
    for (int nt = 0; nt < 4; ++nt) {
      int n0 = (w * 4 + nt) * 16 + lk * 4;
      f32x4 bv = *(const f32x4*)(b1 + n0);
      u16 hs[4];
      #pragma unroll
      for (int j = 0; j < 4; ++j) hs[j] = f2bf(fmaxf(acc1[nt][j] + bv[j], 0.f));
      *(uint2*)(sYh + lr * YS + n0) = make_uint2((uint32_t)hs[0] | ((uint32_t)hs[1] << 16),
                                                 (uint32_t)hs[2] | ((uint32_t)hs[3] << 16));
    }
    __syncthreads();
    f32x4 acc2[4];
    #pragma unroll
    for (int q = 0; q < 4; ++q) acc2[q] = (f32x4){0.f,0.f,0.f,0.f};
    const u16* p2h = w2h + (size_t)(w * 16 + lr) * KY;
    #pragma unroll
    for (int ks2 = 0; ks2 < 20; ++ks2) {
      int k0 = ks2 * 32 + lk * 8;
      bf16x8 yh = *(const bf16x8*)(sYh + lr * YS + k0);
      bf16x8 wh = *(const bf16x8*)(p2h + k0);
      int q = ks2 & 3;
      acc2[q] = MFMA16(wh, yh, acc2[q]);
    }
    f32x4 accs;
    #pragma unroll
    for (int j = 0; j < 4; ++j) accs[j] = (acc2[0][j] + acc2[1][j]) + (acc2[2][j] + acc2[3][j]);
    int n0 = w * 16 + lk * 4;
    f32x4 bv = *(const f32x4*)(b2 + n0);
    float* hp = sH + lr * 164 + n0;
    f32x4 oldv = *(f32x4*)hp;
    #pragma unroll
    for (int j = 0; j < 4; ++j) oldv[j] += fmaxf(accs[j] + bv[j], 0.f);
    *(f32x4*)hp = oldv;
    __syncthreads();
  }
  {
    int r = t / 40, c4 = (t % 40) * 4;
    f32x4 hv = *(const f32x4*)(sH + r * 164 + c4);
    u16 o[4] = {f2bf(hv[0]), f2bf(hv[1]), f2bf(hv[2]), f2bf(hv[3])};
    *(uint2*)(Hh + (size_t)(mb * 16 + r) * KH + c4) = make_uint2((uint32_t)o[0] | ((uint32_t)o[1] << 16),
                                                                 (uint32_t)o[2] | ((uint32_t)o[3] << 16));
  }
}

// ---------------- fc head: BNF=32 tile, 4 blocks/CU (16 waves/CU) ----------------

static __device__ __forceinline__ void fc_load(const u16* __restrict__ g, u32x4* ld, int t) {
  #pragma unroll
  for (int q = 0; q < LD_PER_T; ++q) {
    int idx = t + q * 256;
    if (idx < TILE_LD) ld[q] = *(const u32x4*)(g + idx * 8);
  }
}
static __device__ __forceinline__ void fc_store(u16* __restrict__ s, const u32x4* ld, int t) {
  #pragma unroll
  for (int q = 0; q < LD_PER_T; ++q) {
    int idx = t + q * 256;
    if (idx < TILE_LD) *(u32x4*)(s + idx * 8) = ld[q];
  }
}

template<int PASS>
__global__ __launch_bounds__(256, 4) void fc_k(const u16* __restrict__ Ah, const u16* __restrict__ Wb,
                                               const float* __restrict__ fcb,
                                               float* __restrict__ partial, const float* __restrict__ invr,
                                               float* __restrict__ out) {
  __shared__ __align__(16) u16 sW[2][TILE_U16];   // 2 x 10752 B
  int t = threadIdx.x;
  int mb = blockIdx.x & 15, nc = blockIdx.x >> 4;
  int w = t >> 6, lane = t & 63, lr = lane & 15, lk = lane >> 4;
  int arow = mb * 256 + w * 64;
  bf16x8 af[4][5];
  #pragma unroll
  for (int mt = 0; mt < 4; ++mt) {
    const u16* ap = Ah + (size_t)(arow + mt * 16 + lr) * KH;
    #pragma unroll
    for (int ks = 0; ks < 5; ++ks) af[mt][ks] = *(const bf16x8*)(ap + (ks * 4 + lk) * 8);
  }
  float iv[4];
  float racc[4] = {0.f, 0.f, 0.f, 0.f};
  if (PASS == 2) {
    #pragma unroll
    for (int mt = 0; mt < 4; ++mt) iv[mt] = invr[arow + mt * 16 + lr];
  }
  u32x4 ld[LD_PER_T];
  fc_load(Wb + (size_t)nc * TILE_U16, ld, t);
  fc_store(sW[0], ld, t);
  __syncthreads();
  int cur = 0;
  for (int nb = nc; nb < NSUB; nb += NCHUNK) {
    int nn = nb + NCHUNK;
    if (nn < NSUB) fc_load(Wb + (size_t)nn * TILE_U16, ld, t);
    f32x4 acc[4][2];
    #pragma unroll
    for (int mt = 0; mt < 4; ++mt)
      #pragma unroll
      for (int nt = 0; nt < 2; ++nt) acc[mt][nt] = (f32x4){0.f,0.f,0.f,0.f};
    const u16* sw = sW[cur];
    #pragma unroll
    for (int ks = 0; ks < 5; ++ks) {
      bf16x8 wf[2];
      #pragma unroll
      for (int nt = 0; nt < 2; ++nt)
        wf[nt] = *(const bf16x8*)(sw + (nt * 16 + lr) * KWP + (ks * 4 + lk) * 8);
      #pragma unroll
      for (int mt = 0; mt < 4; ++mt)
        #pragma unroll
        for (int nt = 0; nt < 2; ++nt)
          acc[mt][nt] = MFMA16(wf[nt], af[mt][ks], acc[mt][nt]);
    }
    #pragma unroll
    for (int nt = 0; nt < 2; ++nt) {
      int n0 = nb * 32 + nt * 16 + lk * 4;
      if (n0 < V_) {
        f32x4 bv = *(const f32x4*)(fcb + n0);
        if (PASS == 1) {
          #pragma unroll
          for (int mt = 0; mt < 4; ++mt) {
            racc[mt] += __expf(acc[mt][nt][0] + bv[0]) + __expf(acc[mt][nt][1] + bv[1])
                      + __expf(acc[mt][nt][2] + bv[2]) + __expf(acc[mt][nt][3] + bv[3]);
          }
        } else {
          #pragma unroll
          for (int mt = 0; mt < 4; ++mt) {
            f32x4 v;
            v[0] = __expf(acc[mt][nt][0] + bv[0]) * iv[mt];
            v[1] = __expf(acc[mt][nt][1] + bv[1]) * iv[mt];
            v[2] = __expf(acc[mt][nt][2] + bv[2]) * iv[mt];
            v[3] = __expf(acc[mt][nt][3] + bv[3]) * iv[mt];
            __builtin_nontemporal_store(v, (f32x4*)(out + (size_t)(arow + mt * 16 + lr) * V_ + n0));
          }
        }
      }
    }
    if (nn < NSUB) fc_store(sW[cur ^ 1], ld, t);
    __syncthreads();
    cur ^= 1;
  }
  if (PASS == 1) {
    #pragma unroll
    for (int mt = 0; mt < 4; ++mt) {
      float s = racc[mt];
      s += __shfl_xor(s, 16);
      s += __shfl_xor(s, 32);
      if (lk == 0) partial[(size_t)nc * B_ + arow + mt * 16 + lr] = s;
    }
  }
}

__global__ __launch_bounds__(256) void rowsum_k(const float* __restrict__ partial, float* __restrict__ invr) {
  int r = blockIdx.x * 256 + threadIdx.x;
  float s = 0.f;
  for (int nc = 0; nc < NCHUNK; ++nc) s += partial[(size_t)nc * B_ + r];
  invr[r] = 1.f / s;
}

// ---------------- launcher ----------------

extern "C" void kernel_launch(void* const* d_in, const int* in_sizes, int n_in,
                              void* d_out, int out_size, void* d_ws, size_t ws_size,
                              hipStream_t stream) {
  const float* inp   = (const float*)d_in[0];
  const int*   mask  = (const int*)d_in[1];
  const float* embed = (const float*)d_in[2];
  const float* sw1   = (const float*)d_in[3];
  const float* sb1   = (const float*)d_in[4];
  const float* sw2   = (const float*)d_in[5];
  const float* sb2   = (const float*)d_in[6];
  const float* rw1   = (const float*)d_in[7];
  const float* rb1   = (const float*)d_in[8];
  const float* rw2   = (const float*)d_in[9];
  const float* rb2   = (const float*)d_in[10];
  const float* fcw   = (const float*)d_in[11];
  const float* fcb   = (const float*)d_in[12];
  float* out = (float*)d_out;

  uint8_t* wsb = (uint8_t*)d_ws;
  size_t off = 0;
  auto alloc = [&](size_t bytes) { uint8_t* p = wsb + off; off += (bytes + 255) & ~(size_t)255; return p; };
  u16*   fcwb = (u16*)  alloc((size_t)VP_ * KWP * 2);
  u16*   W1h  = (u16*)  alloc((size_t)6 * KY * KH * 2);
  u16*   W2h  = (u16*)  alloc((size_t)6 * KH * KY * 2);
  float* b1p  = (float*)alloc((size_t)6 * KY * 4);
  float* b2p  = (float*)alloc((size_t)6 * KH * 4);
  float* Hf   = (float*)alloc((size_t)B_ * KH * 4);
  u16*   Hh   = (u16*)  alloc((size_t)B_ * KH * 2);
  float* part = (float*)alloc((size_t)NCHUNK * B_ * 4);
  float* invr = (float*)alloc((size_t)B_ * 4);

  prep_all_k <<<NB_FC + NB_RES + NB_BIA, 256, 0, stream>>>(fcw, fcwb, rw1, rw2, W1h, W2h,
                                                           rb1, rb2, b1p, b2p);
  h0_k       <<<B_, 192, 0, stream>>>(inp, mask, embed, sw1, sb1, sw2, sb2, Hf);
  trunk_k    <<<B_ / 16, 640, 0, stream>>>(W1h, W2h, b1p, b2p, Hf, Hh);
  fc_k<1>  <<<16 * NCHUNK, 256, 0, stream>>>(Hh, fcwb, fcb, part, nullptr, nullptr);
  rowsum_k <<<B_ / 256, 256, 0, stream>>>(part, invr);
  fc_k<2>  <<<16 * NCHUNK, 256, 0, stream>>>(Hh, fcwb, fcb, nullptr, invr, out);
}

// Round 12
// 480.812 us; speedup vs baseline: 1.3573x; 1.3573x over previous
//
#include <hip/hip_runtime.h>
#include <stdint.h>

typedef unsigned short u16;
typedef short bf16x8 __attribute__((ext_vector_type(8)));
typedef float f32x4  __attribute__((ext_vector_type(4)));
typedef uint32_t u32x4 __attribute__((ext_vector_type(4)));

#define MFMA16(a,b,c) __builtin_amdgcn_mfma_f32_16x16x32_bf16((a),(b),(c),0,0,0)

#define B_    4096
#define S_    50
#define V_    50000
#define VP_   50048     // 1564 * 32
#define KH    160       // padded h width (154 -> 160)
#define KY    640       // padded y1 width (616 -> 640)
#define KWP   168       // padded fc-weight row stride (elems)
#define BNF   32        // fc N-subtile rows
#define NMB   32        // fc M-blocks (4096/128)
#define NSUB  1564      // VP_/BNF
#define NCHUNK 32       // fc N-chunks: grid 32*32=1024 -> 4 blocks/CU
#define TILE_U16 (BNF * KWP)        // 5376 elems, 10752 B
#define TILE_LD  (TILE_U16 * 2 / 16) // 672 lane-loads
#define LD_PER_T 3
#define YS    648       // y1 LDS row stride

#define NB_FC  8211     // ceil(VP_*KWP/4/256)
#define NB_RES 4800     // 2*6*KY*KH/256
#define NB_BIA 19

static __device__ __forceinline__ u16 f2bf(float f) {
  union { float f; uint32_t u; } v; v.f = f;
  uint32_t u = v.u;
  return (u16)((u + 0x7FFFu + ((u >> 16) & 1u)) >> 16);   // RNE
}
static __device__ __forceinline__ float bf2f(u16 b) {
  union { uint32_t u; float f; } v; v.u = ((uint32_t)b) << 16; return v.f;
}

// ---------------- merged prep kernel (trunk weights: hi plane only) ----------------

__global__ __launch_bounds__(256) void prep_all_k(const float* __restrict__ fcw, u16* __restrict__ fcwb,
                                                  const float* __restrict__ rw1, const float* __restrict__ rw2,
                                                  u16* __restrict__ W1h, u16* __restrict__ W2h,
                                                  const float* __restrict__ rb1, const float* __restrict__ rb2,
                                                  float* __restrict__ b1p, float* __restrict__ b2p) {
  int bid = blockIdx.x, t = threadIdx.x;
  if (bid < NB_FC) {
    int e4 = (bid * 256 + t) * 4;
    if (e4 >= VP_ * KWP) return;
    int v = e4 / KWP, c = e4 - v * KWP;
    u16 o[4];
    #pragma unroll
    for (int i = 0; i < 4; ++i) {
      float x = (v < V_ && (c + i) < 154) ? fcw[(size_t)v * 154 + c + i] : 0.f;
      o[i] = f2bf(x);
    }
    *(uint2*)(fcwb + e4) = make_uint2((uint32_t)o[0] | ((uint32_t)o[1] << 16),
                                      (uint32_t)o[2] | ((uint32_t)o[3] << 16));
  } else if (bid < NB_FC + NB_RES) {
    int e = (bid - NB_FC) * 256 + t;
    const int NW = 6 * KY * KH;
    if (e < NW) {
      int k = e % KH, n = (e / KH) % KY, i = e / (KH * KY);
      float x = (n < 616 && k < 154) ? rw1[((size_t)i * 616 + n) * 154 + k] : 0.f;
      W1h[e] = f2bf(x);
    } else {
      int e2 = e - NW;
      int k = e2 % KY, n = (e2 / KY) % KH, i = e2 / (KH * KY);
      float x = (n < 154 && k < 616) ? rw2[((size_t)i * 154 + n) * 616 + k] : 0.f;
      W2h[e2] = f2bf(x);
    }
  } else {
    int e = (bid - NB_FC - NB_RES) * 256 + t;
    if (e < 6 * KY) {
      int i = e / KY, n = e % KY;
      b1p[e] = (n < 616) ? rb1[i * 616 + n] : 0.f;
    } else if (e < 6 * KY + 6 * KH) {
      int e2 = e - 6 * KY;
      int i = e2 / KH, n = e2 % KH;
      b2p[e2] = (n < 154) ? rb2[i * 154 + n] : 0.f;
    }
  }
}

// ---------------- h0: embed gather + masked mean + SE gate (f32 out) ----------------

__global__ __launch_bounds__(192) void h0_k(const float* __restrict__ inp, const int* __restrict__ mask,
                                            const float* __restrict__ embed,
                                            const float* __restrict__ sw1, const float* __restrict__ sb1,
                                            const float* __restrict__ sw2, const float* __restrict__ sb2,
                                            float* __restrict__ Hf) {
  int b = blockIdx.x, t = threadIdx.x;
  __shared__ float in_s[S_ * 28];
  __shared__ int   ids[S_];
  __shared__ float h_s[160];
  __shared__ float means[6];
  __shared__ int   len_s;
  const float* row = inp + (size_t)b * S_ * 28;
  for (int i = t; i < S_ * 28; i += 192) in_s[i] = row[i];
  int msum = 0;
  if (t < S_) msum = mask[b * S_ + t];
  __syncthreads();
  if (t < 64) {
    for (int off = 32; off; off >>= 1) msum += __shfl_down(msum, off);
    if (t == 0) len_s = msum;
  }
  if (t < S_) ids[t] = (int)in_s[t * 28];
  __syncthreads();
  int len = len_s;
  if (t < 154) {
    float val;
    if (t < 77) {
      float s = 0.f;
      if (t < 50) { for (int si = 0; si < len; ++si) s += embed[(size_t)ids[si] * 50 + t]; }
      else        { for (int si = 0; si < len; ++si) s += in_s[si * 28 + 1 + (t - 50)]; }
      val = s / (float)len;
    } else {
      int k2 = t - 77;
      val = (k2 < 50) ? embed[(size_t)ids[S_ - 1] * 50 + k2] : in_s[(S_ - 1) * 28 + 1 + (k2 - 50)];
    }
    h_s[t] = val;
  }
  __syncthreads();
  if (t < 6) {
    const int bnd[7] = {0, 50, 56, 77, 127, 133, 154};
    float s = 0.f;
    for (int k = bnd[t]; k < bnd[t + 1]; ++k) s += h_s[k];
    means[t] = s / (float)(bnd[t + 1] - bnd[t]);
  }
  __syncthreads();
  if (t < 160) {
    float o = 0.f;
    if (t < 154) {
      int seg = (t < 50) ? 0 : (t < 56) ? 1 : (t < 77) ? 2 : (t < 127) ? 3 : (t < 133) ? 4 : 5;
      float r0 = sb1[0], r1 = sb1[1];
      #pragma unroll
      for (int j = 0; j < 6; ++j) { r0 += sw1[j] * means[j]; r1 += sw1[6 + j] * means[j]; }
      r0 = fmaxf(r0, 0.f); r1 = fmaxf(r1, 0.f);
      float z = sw2[seg * 2 + 0] * r0 + sw2[seg * 2 + 1] * r1 + sb2[seg];
      float gate = 1.f / (1.f + __expf(-z));
      o = h_s[t] * gate;
    }
    Hf[(size_t)b * KH + t] = o;
  }
}

// ---------------- fused trunk: 6 resblocks, h in f32 LDS, plain bf16 GEMMs ----------------

__global__ __launch_bounds__(640, 1) void trunk_k(const u16* __restrict__ W1h_,
                                                  const u16* __restrict__ W2h_,
                                                  const float* __restrict__ b1p, const float* __restrict__ b2p,
                                                  const float* __restrict__ Hf, u16* __restrict__ Hh) {
  __shared__ __align__(16) float sH[16 * 164];
  __shared__ __align__(16) u16 sYh[16 * YS];
  int t = threadIdx.x, mb = blockIdx.x;
  int w = t >> 6, lane = t & 63, lr = lane & 15, lk = lane >> 4;
  {
    int r = t / 40, c4 = (t % 40) * 4;
    *(f32x4*)(sH + r * 164 + c4) = *(const f32x4*)(Hf + (size_t)(mb * 16 + r) * KH + c4);
  }
  __syncthreads();
  for (int i = 0; i < 6; ++i) {
    const u16* w1h = W1h_ + (size_t)i * KY * KH;
    const u16* w2h = W2h_ + (size_t)i * KH * KY;
    const float* b1 = b1p + i * KY;
    const float* b2 = b2p + i * KH;
    bf16x8 hh[5];
    #pragma unroll
    for (int ks = 0; ks < 5; ++ks) {
      int k0 = ks * 32 + lk * 8;
      f32x4 a = *(const f32x4*)(sH + lr * 164 + k0);
      f32x4 b = *(const f32x4*)(sH + lr * 164 + k0 + 4);
      bf16x8 hv;
      #pragma unroll
      for (int e = 0; e < 4; ++e) {
        hv[e] = (short)f2bf(a[e]);
        hv[4 + e] = (short)f2bf(b[e]);
      }
      hh[ks] = hv;
    }
    f32x4 acc1[4];
    #pragma unroll
    for (int nt = 0; nt < 4; ++nt) acc1[nt] = (f32x4){0.f,0.f,0.f,0.f};
    #pragma unroll
    for (int ks = 0; ks < 5; ++ks) {
      int k0 = ks * 32 + lk * 8;
      #pragma unroll
      for (int nt = 0; nt < 4; ++nt) {
        size_t ro = (size_t)((w * 4 + nt) * 16 + lr) * KH + k0;
        bf16x8 wh = *(const bf16x8*)(w1h + ro);
        acc1[nt] = MFMA16(wh, hh[ks], acc1[nt]);
      }
    }
    #pragma unroll
    for (int nt = 0; nt < 4; ++nt) {
      int n0 = (w * 4 + nt) * 16 + lk * 4;
      f32x4 bv = *(const f32x4*)(b1 + n0);
      u16 hs[4];
      #pragma unroll
      for (int j = 0; j < 4; ++j) hs[j] = f2bf(fmaxf(acc1[nt][j] + bv[j], 0.f));
      *(uint2*)(sYh + lr * YS + n0) = make_uint2((uint32_t)hs[0] | ((uint32_t)hs[1] << 16),
                                                 (uint32_t)hs[2] | ((uint32_t)hs[3] << 16));
    }
    __syncthreads();
    f32x4 acc2[4];
    #pragma unroll
    for (int q = 0; q < 4; ++q) acc2[q] = (f32x4){0.f,0.f,0.f,0.f};
    const u16* p2h = w2h + (size_t)(w * 16 + lr) * KY;
    #pragma unroll
    for (int ks2 = 0; ks2 < 20; ++ks2) {
      int k0 = ks2 * 32 + lk * 8;
      bf16x8 yh = *(const bf16x8*)(sYh + lr * YS + k0);
      bf16x8 wh = *(const bf16x8*)(p2h + k0);
      int q = ks2 & 3;
      acc2[q] = MFMA16(wh, yh, acc2[q]);
    }
    f32x4 accs;
    #pragma unroll
    for (int j = 0; j < 4; ++j) accs[j] = (acc2[0][j] + acc2[1][j]) + (acc2[2][j] + acc2[3][j]);
    int n0 = w * 16 + lk * 4;
    f32x4 bv = *(const f32x4*)(b2 + n0);
    float* hp = sH + lr * 164 + n0;
    f32x4 oldv = *(f32x4*)hp;
    #pragma unroll
    for (int j = 0; j < 4; ++j) oldv[j] += fmaxf(accs[j] + bv[j], 0.f);
    *(f32x4*)hp = oldv;
    __syncthreads();
  }
  {
    int r = t / 40, c4 = (t % 40) * 4;
    f32x4 hv = *(const f32x4*)(sH + r * 164 + c4);
    u16 o[4] = {f2bf(hv[0]), f2bf(hv[1]), f2bf(hv[2]), f2bf(hv[3])};
    *(uint2*)(Hh + (size_t)(mb * 16 + r) * KH + c4) = make_uint2((uint32_t)o[0] | ((uint32_t)o[1] << 16),
                                                                 (uint32_t)o[2] | ((uint32_t)o[3] << 16));
  }
}

// ---------------- fc head: BM=128, BNF=32 -> ~120 natural VGPR, 3-4 blocks/CU ----------------

static __device__ __forceinline__ void fc_load(const u16* __restrict__ g, u32x4* ld, int t) {
  #pragma unroll
  for (int q = 0; q < LD_PER_T; ++q) {
    int idx = t + q * 256;
    if (idx < TILE_LD) ld[q] = *(const u32x4*)(g + idx * 8);
  }
}
static __device__ __forceinline__ void fc_store(u16* __restrict__ s, const u32x4* ld, int t) {
  #pragma unroll
  for (int q = 0; q < LD_PER_T; ++q) {
    int idx = t + q * 256;
    if (idx < TILE_LD) *(u32x4*)(s + idx * 8) = ld[q];
  }
}

template<int PASS>
__global__ __launch_bounds__(256, 2) void fc_k(const u16* __restrict__ Ah, const u16* __restrict__ Wb,
                                               const float* __restrict__ fcb,
                                               float* __restrict__ partial, const float* __restrict__ invr,
                                               float* __restrict__ out) {
  __shared__ __align__(16) u16 sW[2][TILE_U16];   // 2 x 10752 B
  int t = threadIdx.x;
  int mb = blockIdx.x & (NMB - 1), nc = blockIdx.x / NMB;
  int w = t >> 6, lane = t & 63, lr = lane & 15, lk = lane >> 4;
  int arow = mb * 128 + w * 32;
  bf16x8 af[2][5];
  #pragma unroll
  for (int mt = 0; mt < 2; ++mt) {
    const u16* ap = Ah + (size_t)(arow + mt * 16 + lr) * KH;
    #pragma unroll
    for (int ks = 0; ks < 5; ++ks) af[mt][ks] = *(const bf16x8*)(ap + (ks * 4 + lk) * 8);
  }
  float iv[2];
  float racc[2] = {0.f, 0.f};
  if (PASS == 2) {
    #pragma unroll
    for (int mt = 0; mt < 2; ++mt) iv[mt] = invr[arow + mt * 16 + lr];
  }
  u32x4 ld[LD_PER_T];
  fc_load(Wb + (size_t)nc * TILE_U16, ld, t);
  fc_store(sW[0], ld, t);
  __syncthreads();
  int cur = 0;
  for (int nb = nc; nb < NSUB; nb += NCHUNK) {
    int nn = nb + NCHUNK;
    if (nn < NSUB) fc_load(Wb + (size_t)nn * TILE_U16, ld, t);
    f32x4 acc[2][2];
    #pragma unroll
    for (int mt = 0; mt < 2; ++mt)
      #pragma unroll
      for (int nt = 0; nt < 2; ++nt) acc[mt][nt] = (f32x4){0.f,0.f,0.f,0.f};
    const u16* sw = sW[cur];
    #pragma unroll
    for (int ks = 0; ks < 5; ++ks) {
      bf16x8 wf[2];
      #pragma unroll
      for (int nt = 0; nt < 2; ++nt)
        wf[nt] = *(const bf16x8*)(sw + (nt * 16 + lr) * KWP + (ks * 4 + lk) * 8);
      #pragma unroll
      for (int mt = 0; mt < 2; ++mt)
        #pragma unroll
        for (int nt = 0; nt < 2; ++nt)
          acc[mt][nt] = MFMA16(wf[nt], af[mt][ks], acc[mt][nt]);
    }
    #pragma unroll
    for (int nt = 0; nt < 2; ++nt) {
      int n0 = nb * 32 + nt * 16 + lk * 4;
      if (n0 < V_) {
        f32x4 bv = *(const f32x4*)(fcb + n0);
        if (PASS == 1) {
          #pragma unroll
          for (int mt = 0; mt < 2; ++mt) {
            racc[mt] += __expf(acc[mt][nt][0] + bv[0]) + __expf(acc[mt][nt][1] + bv[1])
                      + __expf(acc[mt][nt][2] + bv[2]) + __expf(acc[mt][nt][3] + bv[3]);
          }
        } else {
          #pragma unroll
          for (int mt = 0; mt < 2; ++mt) {
            f32x4 v;
            v[0] = __expf(acc[mt][nt][0] + bv[0]) * iv[mt];
            v[1] = __expf(acc[mt][nt][1] + bv[1]) * iv[mt];
            v[2] = __expf(acc[mt][nt][2] + bv[2]) * iv[mt];
            v[3] = __expf(acc[mt][nt][3] + bv[3]) * iv[mt];
            __builtin_nontemporal_store(v, (f32x4*)(out + (size_t)(arow + mt * 16 + lr) * V_ + n0));
          }
        }
      }
    }
    if (nn < NSUB) fc_store(sW[cur ^ 1], ld, t);
    __syncthreads();
    cur ^= 1;
  }
  if (PASS == 1) {
    #pragma unroll
    for (int mt = 0; mt < 2; ++mt) {
      float s = racc[mt];
      s += __shfl_xor(s, 16);
      s += __shfl_xor(s, 32);
      if (lk == 0) partial[(size_t)nc * B_ + arow + mt * 16 + lr] = s;
    }
  }
}

__global__ __launch_bounds__(256) void rowsum_k(const float* __restrict__ partial, float* __restrict__ invr) {
  int r = blockIdx.x * 256 + threadIdx.x;
  float s = 0.f;
  for (int nc = 0; nc < NCHUNK; ++nc) s += partial[(size_t)nc * B_ + r];
  invr[r] = 1.f / s;
}

// ---------------- launcher ----------------

extern "C" void kernel_launch(void* const* d_in, const int* in_sizes, int n_in,
                              void* d_out, int out_size, void* d_ws, size_t ws_size,
                              hipStream_t stream) {
  const float* inp   = (const float*)d_in[0];
  const int*   mask  = (const int*)d_in[1];
  const float* embed = (const float*)d_in[2];
  const float* sw1   = (const float*)d_in[3];
  const float* sb1   = (const float*)d_in[4];
  const float* sw2   = (const float*)d_in[5];
  const float* sb2   = (const float*)d_in[6];
  const float* rw1   = (const float*)d_in[7];
  const float* rb1   = (const float*)d_in[8];
  const float* rw2   = (const float*)d_in[9];
  const float* rb2   = (const float*)d_in[10];
  const float* fcw   = (const float*)d_in[11];
  const float* fcb   = (const float*)d_in[12];
  float* out = (float*)d_out;

  uint8_t* wsb = (uint8_t*)d_ws;
  size_t off = 0;
  auto alloc = [&](size_t bytes) { uint8_t* p = wsb + off; off += (bytes + 255) & ~(size_t)255; return p; };
  u16*   fcwb = (u16*)  alloc((size_t)VP_ * KWP * 2);
  u16*   W1h  = (u16*)  alloc((size_t)6 * KY * KH * 2);
  u16*   W2h  = (u16*)  alloc((size_t)6 * KH * KY * 2);
  float* b1p  = (float*)alloc((size_t)6 * KY * 4);
  float* b2p  = (float*)alloc((size_t)6 * KH * 4);
  float* Hf   = (float*)alloc((size_t)B_ * KH * 4);
  u16*   Hh   = (u16*)  alloc((size_t)B_ * KH * 2);
  float* part = (float*)alloc((size_t)NCHUNK * B_ * 4);
  float* invr = (float*)alloc((size_t)B_ * 4);

  prep_all_k <<<NB_FC + NB_RES + NB_BIA, 256, 0, stream>>>(fcw, fcwb, rw1, rw2, W1h, W2h,
                                                           rb1, rb2, b1p, b2p);
  h0_k       <<<B_, 192, 0, stream>>>(inp, mask, embed, sw1, sb1, sw2, sb2, Hf);
  trunk_k    <<<B_ / 16, 640, 0, stream>>>(W1h, W2h, b1p, b2p, Hf, Hh);
  fc_k<1>  <<<NMB * NCHUNK, 256, 0, stream>>>(Hh, fcwb, fcb, part, nullptr, nullptr);
  rowsum_k <<<B_ / 256, 256, 0, stream>>>(part, invr);
  fc_k<2>  <<<NMB * NCHUNK, 256, 0, stream>>>(Hh, fcwb, fcb, nullptr, invr, out);
}

// Round 13
// 457.686 us; speedup vs baseline: 1.4259x; 1.0505x over previous
//
#include <hip/hip_runtime.h>
#include <stdint.h>

typedef unsigned short u16;
typedef short bf16x8 __attribute__((ext_vector_type(8)));
typedef float f32x4  __attribute__((ext_vector_type(4)));
typedef uint32_t u32x4 __attribute__((ext_vector_type(4)));

#define MFMA16(a,b,c) __builtin_amdgcn_mfma_f32_16x16x32_bf16((a),(b),(c),0,0,0)

#define B_    4096
#define S_    50
#define V_    50000
#define VP_   50048     // 782 * 64
#define KH    160       // padded h width (154 -> 160)
#define KY    640       // padded y1 width (616 -> 640)
#define KWP   168       // padded fc-weight row stride (elems)
#define BNF   64        // fc N-subtile rows
#define NSUB  782       // VP_/BNF
#define NCHUNK 32       // fc N-chunks (grid dim)
#define TILE_U16 (BNF * KWP)
#define TILE_LD  (TILE_U16 * 2 / 16)
#define LD_PER_T 6
#define YS    648       // y1 LDS row stride

#define NB_FC  8211     // ceil(VP_*KWP/4/256)
#define NB_RES 4800     // 2*6*KY*KH/256
#define NB_BIA 19
#define NB_PRE (NB_FC + NB_RES + NB_BIA)

static __device__ __forceinline__ u16 f2bf(float f) {
  union { float f; uint32_t u; } v; v.f = f;
  uint32_t u = v.u;
  return (u16)((u + 0x7FFFu + ((u >> 16) & 1u)) >> 16);   // RNE
}
static __device__ __forceinline__ float bf2f(u16 b) {
  union { uint32_t u; float f; } v; v.u = ((uint32_t)b) << 16; return v.f;
}

// ---------------- merged prep + h0 kernel ----------------
// Ranges: [0,NB_FC) fc-weight bf16 pack; [NB_FC,NB_FC+NB_RES) trunk W hi-plane;
// [.., +NB_BIA) bias pad; [NB_PRE, NB_PRE+B_) h0 (independent of prep outputs).

__global__ __launch_bounds__(256) void prep_all_k(const float* __restrict__ fcw, u16* __restrict__ fcwb,
                                                  const float* __restrict__ rw1, const float* __restrict__ rw2,
                                                  u16* __restrict__ W1h, u16* __restrict__ W2h,
                                                  const float* __restrict__ rb1, const float* __restrict__ rb2,
                                                  float* __restrict__ b1p, float* __restrict__ b2p,
                                                  const float* __restrict__ inp, const int* __restrict__ mask,
                                                  const float* __restrict__ embed,
                                                  const float* __restrict__ sw1, const float* __restrict__ sb1,
                                                  const float* __restrict__ sw2, const float* __restrict__ sb2,
                                                  float* __restrict__ Hf) {
  int bid = blockIdx.x, t = threadIdx.x;
  if (bid < NB_FC) {
    int e4 = (bid * 256 + t) * 4;
    if (e4 >= VP_ * KWP) return;
    int v = e4 / KWP, c = e4 - v * KWP;
    u16 o[4];
    #pragma unroll
    for (int i = 0; i < 4; ++i) {
      float x = (v < V_ && (c + i) < 154) ? fcw[(size_t)v * 154 + c + i] : 0.f;
      o[i] = f2bf(x);
    }
    *(uint2*)(fcwb + e4) = make_uint2((uint32_t)o[0] | ((uint32_t)o[1] << 16),
                                      (uint32_t)o[2] | ((uint32_t)o[3] << 16));
  } else if (bid < NB_FC + NB_RES) {
    int e = (bid - NB_FC) * 256 + t;
    const int NW = 6 * KY * KH;
    if (e < NW) {
      int k = e % KH, n = (e / KH) % KY, i = e / (KH * KY);
      float x = (n < 616 && k < 154) ? rw1[((size_t)i * 616 + n) * 154 + k] : 0.f;
      W1h[e] = f2bf(x);
    } else {
      int e2 = e - NW;
      int k = e2 % KY, n = (e2 / KY) % KH, i = e2 / (KH * KY);
      float x = (n < 154 && k < 616) ? rw2[((size_t)i * 154 + n) * 616 + k] : 0.f;
      W2h[e2] = f2bf(x);
    }
  } else if (bid < NB_PRE) {
    int e = (bid - NB_FC - NB_RES) * 256 + t;
    if (e < 6 * KY) {
      int i = e / KY, n = e % KY;
      b1p[e] = (n < 616) ? rb1[i * 616 + n] : 0.f;
    } else if (e < 6 * KY + 6 * KH) {
      int e2 = e - 6 * KY;
      int i = e2 / KH, n = e2 % KH;
      b2p[e2] = (n < 154) ? rb2[i * 154 + n] : 0.f;
    }
  } else {
    // ---- h0 range ----
    int b = bid - NB_PRE;
    __shared__ float in_s[S_ * 28];
    __shared__ int   ids[S_];
    __shared__ float h_s[160];
    __shared__ float means[6];
    __shared__ int   len_s;
    const float* row = inp + (size_t)b * S_ * 28;
    for (int i = t; i < S_ * 28; i += 256) in_s[i] = row[i];
    int msum = 0;
    if (t < S_) msum = mask[b * S_ + t];
    __syncthreads();
    if (t < 64) {
      for (int off = 32; off; off >>= 1) msum += __shfl_down(msum, off);
      if (t == 0) len_s = msum;
    }
    if (t < S_) ids[t] = (int)in_s[t * 28];
    __syncthreads();
    int len = len_s;
    if (t < 154) {
      float val;
      if (t < 77) {
        float s = 0.f;
        if (t < 50) { for (int si = 0; si < len; ++si) s += embed[(size_t)ids[si] * 50 + t]; }
        else        { for (int si = 0; si < len; ++si) s += in_s[si * 28 + 1 + (t - 50)]; }
        val = s / (float)len;
      } else {
        int k2 = t - 77;
        val = (k2 < 50) ? embed[(size_t)ids[S_ - 1] * 50 + k2] : in_s[(S_ - 1) * 28 + 1 + (k2 - 50)];
      }
      h_s[t] = val;
    }
    __syncthreads();
    if (t < 6) {
      const int bnd[7] = {0, 50, 56, 77, 127, 133, 154};
      float s = 0.f;
      for (int k = bnd[t]; k < bnd[t + 1]; ++k) s += h_s[k];
      means[t] = s / (float)(bnd[t + 1] - bnd[t]);
    }
    __syncthreads();
    if (t < 160) {
      float o = 0.f;
      if (t < 154) {
        int seg = (t < 50) ? 0 : (t < 56) ? 1 : (t < 77) ? 2 : (t < 127) ? 3 : (t < 133) ? 4 : 5;
        float r0 = sb1[0], r1 = sb1[1];
        #pragma unroll
        for (int j = 0; j < 6; ++j) { r0 += sw1[j] * means[j]; r1 += sw1[6 + j] * means[j]; }
        r0 = fmaxf(r0, 0.f); r1 = fmaxf(r1, 0.f);
        float z = sw2[seg * 2 + 0] * r0 + sw2[seg * 2 + 1] * r1 + sb2[seg];
        float gate = 1.f / (1.f + __expf(-z));
        o = h_s[t] * gate;
      }
      Hf[(size_t)b * KH + t] = o;
    }
  }
}

// ---------------- fused trunk: 6 resblocks, h in f32 LDS, plain bf16 GEMMs ----------------

__global__ __launch_bounds__(640, 1) void trunk_k(const u16* __restrict__ W1h_,
                                                  const u16* __restrict__ W2h_,
                                                  const float* __restrict__ b1p, const float* __restrict__ b2p,
                                                  const float* __restrict__ Hf, u16* __restrict__ Hh) {
  __shared__ __align__(16) float sH[16 * 164];
  __shared__ __align__(16) u16 sYh[16 * YS];
  int t = threadIdx.x, mb = blockIdx.x;
  int w = t >> 6, lane = t & 63, lr = lane & 15, lk = lane >> 4;
  {
    int r = t / 40, c4 = (t % 40) * 4;
    *(f32x4*)(sH + r * 164 + c4) = *(const f32x4*)(Hf + (size_t)(mb * 16 + r) * KH + c4);
  }
  __syncthreads();
  for (int i = 0; i < 6; ++i) {
    const u16* w1h = W1h_ + (size_t)i * KY * KH;
    const u16* w2h = W2h_ + (size_t)i * KH * KY;
    const float* b1 = b1p + i * KY;
    const float* b2 = b2p + i * KH;
    bf16x8 hh[5];
    #pragma unroll
    for (int ks = 0; ks < 5; ++ks) {
      int k0 = ks * 32 + lk * 8;
      f32x4 a = *(const f32x4*)(sH + lr * 164 + k0);
      f32x4 b = *(const f32x4*)(sH + lr * 164 + k0 + 4);
      bf16x8 hv;
      #pragma unroll
      for (int e = 0; e < 4; ++e) {
        hv[e] = (short)f2bf(a[e]);
        hv[4 + e] = (short)f2bf(b[e]);
      }
      hh[ks] = hv;
    }
    f32x4 acc1[4];
    #pragma unroll
    for (int nt = 0; nt < 4; ++nt) acc1[nt] = (f32x4){0.f,0.f,0.f,0.f};
    #pragma unroll
    for (int ks = 0; ks < 5; ++ks) {
      int k0 = ks * 32 + lk * 8;
      #pragma unroll
      for (int nt = 0; nt < 4; ++nt) {
        size_t ro = (size_t)((w * 4 + nt) * 16 + lr) * KH + k0;
        bf16x8 wh = *(const bf16x8*)(w1h + ro);
        acc1[nt] = MFMA16(wh, hh[ks], acc1[nt]);
      }
    }
    #pragma unroll
    for (int nt = 0; nt < 4; ++nt) {
      int n0 = (w * 4 + nt) * 16 + lk * 4;
      f32x4 bv = *(const f32x4*)(b1 + n0);
      u16 hs[4];
      #pragma unroll
      for (int j = 0; j < 4; ++j) hs[j] = f2bf(fmaxf(acc1[nt][j] + bv[j], 0.f));
      *(uint2*)(sYh + lr * YS + n0) = make_uint2((uint32_t)hs[0] | ((uint32_t)hs[1] << 16),
                                                 (uint32_t)hs[2] | ((uint32_t)hs[3] << 16));
    }
    __syncthreads();
    f32x4 acc2[4];
    #pragma unroll
    for (int q = 0; q < 4; ++q) acc2[q] = (f32x4){0.f,0.f,0.f,0.f};
    const u16* p2h = w2h + (size_t)(w * 16 + lr) * KY;
    #pragma unroll
    for (int ks2 = 0; ks2 < 20; ++ks2) {
      int k0 = ks2 * 32 + lk * 8;
      bf16x8 yh = *(const bf16x8*)(sYh + lr * YS + k0);
      bf16x8 wh = *(const bf16x8*)(p2h + k0);
      int q = ks2 & 3;
      acc2[q] = MFMA16(wh, yh, acc2[q]);
    }
    f32x4 accs;
    #pragma unroll
    for (int j = 0; j < 4; ++j) accs[j] = (acc2[0][j] + acc2[1][j]) + (acc2[2][j] + acc2[3][j]);
    int n0 = w * 16 + lk * 4;
    f32x4 bv = *(const f32x4*)(b2 + n0);
    float* hp = sH + lr * 164 + n0;
    f32x4 oldv = *(f32x4*)hp;
    #pragma unroll
    for (int j = 0; j < 4; ++j) oldv[j] += fmaxf(accs[j] + bv[j], 0.f);
    *(f32x4*)hp = oldv;
    __syncthreads();
  }
  {
    int r = t / 40, c4 = (t % 40) * 4;
    f32x4 hv = *(const f32x4*)(sH + r * 164 + c4);
    u16 o[4] = {f2bf(hv[0]), f2bf(hv[1]), f2bf(hv[2]), f2bf(hv[3])};
    *(uint2*)(Hh + (size_t)(mb * 16 + r) * KH + c4) = make_uint2((uint32_t)o[0] | ((uint32_t)o[1] << 16),
                                                                 (uint32_t)o[2] | ((uint32_t)o[3] << 16));
  }
}

// ---------------- fc head: A-in-regs, W-streamed double-buffered LDS (R9 config) ----------------

static __device__ __forceinline__ void fc_load(const u16* __restrict__ g, u32x4* ld, int t) {
  #pragma unroll
  for (int q = 0; q < LD_PER_T; ++q) {
    int idx = t + q * 256;
    if (idx < TILE_LD) ld[q] = *(const u32x4*)(g + idx * 8);
  }
}
static __device__ __forceinline__ void fc_store(u16* __restrict__ s, const u32x4* ld, int t) {
  #pragma unroll
  for (int q = 0; q < LD_PER_T; ++q) {
    int idx = t + q * 256;
    if (idx < TILE_LD) *(u32x4*)(s + idx * 8) = ld[q];
  }
}

template<int PASS>
__global__ __launch_bounds__(256, 2) void fc_k(const u16* __restrict__ Ah, const u16* __restrict__ Wb,
                                               const float* __restrict__ fcb,
                                               float* __restrict__ partial, const float* __restrict__ invr,
                                               float* __restrict__ out) {
  __shared__ __align__(16) u16 sW[2][TILE_U16];
  int t = threadIdx.x;
  int mb = blockIdx.x & 15, nc = blockIdx.x >> 4;
  int w = t >> 6, lane = t & 63, lr = lane & 15, lk = lane >> 4;
  int arow = mb * 256 + w * 64;
  bf16x8 af[4][5];
  #pragma unroll
  for (int mt = 0; mt < 4; ++mt) {
    const u16* ap = Ah + (size_t)(arow + mt * 16 + lr) * KH;
    #pragma unroll
    for (int ks = 0; ks < 5; ++ks) af[mt][ks] = *(const bf16x8*)(ap + (ks * 4 + lk) * 8);
  }
  float iv[4];
  float racc[4] = {0.f, 0.f, 0.f, 0.f};
  if (PASS == 2) {
    #pragma unroll
    for (int mt = 0; mt < 4; ++mt) iv[mt] = invr[arow + mt * 16 + lr];
  }
  u32x4 ld[LD_PER_T];
  fc_load(Wb + (size_t)nc * TILE_U16, ld, t);
  fc_store(sW[0], ld, t);
  __syncthreads();
  int cur = 0;
  for (int nb = nc; nb < NSUB; nb += NCHUNK) {
    int nn = nb + NCHUNK;
    if (nn < NSUB) fc_load(Wb + (size_t)nn * TILE_U16, ld, t);
    f32x4 acc[4][4];
    #pragma unroll
    for (int mt = 0; mt < 4; ++mt)
      #pragma unroll
      for (int nt = 0; nt < 4; ++nt) acc[mt][nt] = (f32x4){0.f,0.f,0.f,0.f};
    const u16* sw = sW[cur];
    #pragma unroll
    for (int ks = 0; ks < 5; ++ks) {
      bf16x8 wf[4];
      #pragma unroll
      for (int nt = 0; nt < 4; ++nt)
        wf[nt] = *(const bf16x8*)(sw + (nt * 16 + lr) * KWP + (ks * 4 + lk) * 8);
      #pragma unroll
      for (int mt = 0; mt < 4; ++mt)
        #pragma unroll
        for (int nt = 0; nt < 4; ++nt)
          acc[mt][nt] = MFMA16(wf[nt], af[mt][ks], acc[mt][nt]);
    }
    #pragma unroll
    for (int nt = 0; nt < 4; ++nt) {
      int n0 = nb * 64 + nt * 16 + lk * 4;
      if (n0 < V_) {
        f32x4 bv = *(const f32x4*)(fcb + n0);
        if (PASS == 1) {
          #pragma unroll
          for (int mt = 0; mt < 4; ++mt) {
            racc[mt] += __expf(acc[mt][nt][0] + bv[0]) + __expf(acc[mt][nt][1] + bv[1])
                      + __expf(acc[mt][nt][2] + bv[2]) + __expf(acc[mt][nt][3] + bv[3]);
          }
        } else {
          #pragma unroll
          for (int mt = 0; mt < 4; ++mt) {
            f32x4 v;
            v[0] = __expf(acc[mt][nt][0] + bv[0]) * iv[mt];
            v[1] = __expf(acc[mt][nt][1] + bv[1]) * iv[mt];
            v[2] = __expf(acc[mt][nt][2] + bv[2]) * iv[mt];
            v[3] = __expf(acc[mt][nt][3] + bv[3]) * iv[mt];
            __builtin_nontemporal_store(v, (f32x4*)(out + (size_t)(arow + mt * 16 + lr) * V_ + n0));
          }
        }
      }
    }
    if (nn < NSUB) fc_store(sW[cur ^ 1], ld, t);
    __syncthreads();
    cur ^= 1;
  }
  if (PASS == 1) {
    #pragma unroll
    for (int mt = 0; mt < 4; ++mt) {
      float s = racc[mt];
      s += __shfl_xor(s, 16);
      s += __shfl_xor(s, 32);
      if (lk == 0) partial[(size_t)nc * B_ + arow + mt * 16 + lr] = s;
    }
  }
}

__global__ __launch_bounds__(256) void rowsum_k(const float* __restrict__ partial, float* __restrict__ invr) {
  int r = blockIdx.x * 256 + threadIdx.x;
  float s = 0.f;
  for (int nc = 0; nc < NCHUNK; ++nc) s += partial[(size_t)nc * B_ + r];
  invr[r] = 1.f / s;
}

// ---------------- launcher ----------------

extern "C" void kernel_launch(void* const* d_in, const int* in_sizes, int n_in,
                              void* d_out, int out_size, void* d_ws, size_t ws_size,
                              hipStream_t stream) {
  const float* inp   = (const float*)d_in[0];
  const int*   mask  = (const int*)d_in[1];
  const float* embed = (const float*)d_in[2];
  const float* sw1   = (const float*)d_in[3];
  const float* sb1   = (const float*)d_in[4];
  const float* sw2   = (const float*)d_in[5];
  const float* sb2   = (const float*)d_in[6];
  const float* rw1   = (const float*)d_in[7];
  const float* rb1   = (const float*)d_in[8];
  const float* rw2   = (const float*)d_in[9];
  const float* rb2   = (const float*)d_in[10];
  const float* fcw   = (const float*)d_in[11];
  const float* fcb   = (const float*)d_in[12];
  float* out = (float*)d_out;

  uint8_t* wsb = (uint8_t*)d_ws;
  size_t off = 0;
  auto alloc = [&](size_t bytes) { uint8_t* p = wsb + off; off += (bytes + 255) & ~(size_t)255; return p; };
  u16*   fcwb = (u16*)  alloc((size_t)VP_ * KWP * 2);
  u16*   W1h  = (u16*)  alloc((size_t)6 * KY * KH * 2);
  u16*   W2h  = (u16*)  alloc((size_t)6 * KH * KY * 2);
  float* b1p  = (float*)alloc((size_t)6 * KY * 4);
  float* b2p  = (float*)alloc((size_t)6 * KH * 4);
  float* Hf   = (float*)alloc((size_t)B_ * KH * 4);
  u16*   Hh   = (u16*)  alloc((size_t)B_ * KH * 2);
  float* part = (float*)alloc((size_t)NCHUNK * B_ * 4);
  float* invr = (float*)alloc((size_t)B_ * 4);

  prep_all_k <<<NB_PRE + B_, 256, 0, stream>>>(fcw, fcwb, rw1, rw2, W1h, W2h,
                                               rb1, rb2, b1p, b2p,
                                               inp, mask, embed, sw1, sb1, sw2, sb2, Hf);
  trunk_k    <<<B_ / 16, 640, 0, stream>>>(W1h, W2h, b1p, b2p, Hf, Hh);
  fc_k<1>  <<<16 * NCHUNK, 256, 0, stream>>>(Hh, fcwb, fcb, part, nullptr, nullptr);
  rowsum_k <<<B_ / 256, 256, 0, stream>>>(part, invr);
  fc_k<2>  <<<16 * NCHUNK, 256, 0, stream>>>(Hh, fcwb, fcb, nullptr, invr, out);
}